// Round 18
// baseline (197.088 us; speedup 1.0000x reference)
//
#include <hip/hip_runtime.h>

typedef unsigned short u16;
typedef float f32x4 __attribute__((ext_vector_type(4)));
typedef float f32x16 __attribute__((ext_vector_type(16)));
typedef short bf16x8 __attribute__((ext_vector_type(8)));
typedef int i32x2 __attribute__((ext_vector_type(2)));

__device__ __forceinline__ u16 f2bf(float f){
  union { float f; unsigned u; } x; x.f = f;
  unsigned r = (x.u + 0x7FFFu + ((x.u >> 16) & 1u)) >> 16;
  return (u16)r;
}

// packed bf16 convert: dst.lo = bf16(lo), dst.hi = bf16(hi)  [verified round 4]
__device__ __forceinline__ unsigned cvtpk(float lo, float hi){
  unsigned r;
  asm("v_cvt_pk_bf16_f32 %0, %1, %2" : "=v"(r) : "v"(lo), "v"(hi));
  return r;
}

// 4x guarded raw v_exp_f32 (D = 2^S0). TRANS->TRANS back-to-back needs no
// wait state; one s_nop 1 closes the TRANS->VALU hazard for the tail def.
__device__ __forceinline__ void exp4q(float& a, float& b, float& c, float& d){
  asm("v_exp_f32 %0, %0\n\t"
      "v_exp_f32 %1, %1\n\t"
      "v_exp_f32 %2, %2\n\t"
      "v_exp_f32 %3, %3\n\t"
      "s_nop 1"
      : "+v"(a), "+v"(b), "+v"(c), "+v"(d));
}

__device__ __forceinline__ f32x4 mfma_bf16(bf16x8 a, bf16x8 b, f32x4 c){
  return __builtin_amdgcn_mfma_f32_16x16x32_bf16(a, b, c, 0, 0, 0);
}

__device__ __forceinline__ f32x16 mfma32(bf16x8 a, bf16x8 b, f32x16 c){
  return __builtin_amdgcn_mfma_f32_32x32x16_bf16(a, b, c, 0, 0, 0);
}

__device__ __forceinline__ void gload16(const u16* g, u16* l){
  __builtin_amdgcn_global_load_lds((__attribute__((address_space(1))) void*)g,
                                   (__attribute__((address_space(3))) void*)l, 16, 0, 0);
}

// ---------------- fused fp32 -> bf16 converts (x, qkv_w, o_w in one launch) ----
__global__ void cvt_all(const float* __restrict__ x, const float* __restrict__ w1,
                        const float* __restrict__ w2,
                        u16* __restrict__ ox, u16* __restrict__ o1, u16* __restrict__ o2,
                        int nx4, int n14, int n24){
  int stride = gridDim.x * blockDim.x;
  int ntot = nx4 + n14 + n24;
  for (int i = blockIdx.x*blockDim.x + threadIdx.x; i < ntot; i += stride){
    const float* src; u16* dst; int j = i;
    if (j < nx4){ src = x; dst = ox; }
    else if (j < nx4 + n14){ j -= nx4; src = w1; dst = o1; }
    else { j -= nx4 + n14; src = w2; dst = o2; }
    float4 v = ((const float4*)src)[j];
    ushort4 o;
    o.x = f2bf(v.x); o.y = f2bf(v.y); o.z = f2bf(v.z); o.w = f2bf(v.w);
    ((ushort4*)dst)[j] = o;
  }
}

// Generic 16B-chunk stager for [rows][32] bf16 tiles (4 slots/row, slot ^= row&3).
template<int NCH, int NTHR>
__device__ __forceinline__ void stage32(const u16* src, int ld, u16* lds, int tid){
#pragma unroll
  for (int i = 0; i < NCH/NTHR; i++){
    int c = i*NTHR + tid;
    int row = c >> 2, slot = c & 3;
    int col = ((slot ^ (row & 3)) << 3);
    gload16(src + (size_t)row*ld + col, lds + ((size_t)(c & ~63) << 3));
  }
}

// 64x64 bf16 tile stager (8 slots/row, slot ^= row&7).
template<int NTHR>
__device__ __forceinline__ void stage64(const u16* src, int ld, u16* lds, int tid){
#pragma unroll
  for (int i = 0; i < 512/NTHR; i++){
    int c = i*NTHR + tid;
    int row = c >> 3, slot = c & 7;
    int col = ((slot ^ (row & 7)) << 3);
    gload16(src + (size_t)row*ld + col, lds + ((size_t)(c & ~63) << 3));
  }
}

// ---------- o-proj GEMM (proven 128x128 2-phase path) ----------
__launch_bounds__(256)
__global__ void gemm_bt1(const u16* __restrict__ A, const u16* __restrict__ Bw,
                         const float* __restrict__ bias, float* __restrict__ Co,
                         int M, int Nf, int K)
{
  __shared__ u16 lsA[2][128*32];
  __shared__ u16 lsB[2][128*32];
  int tid = threadIdx.x;
  int wave = tid >> 6, lane = tid & 63, grp = lane >> 4, l16 = lane & 15;
  int ntn = Nf >> 7;
  int bm = blockIdx.x / ntn, bn = blockIdx.x % ntn;
  const u16* Ab = A + (size_t)bm*128*K;
  const u16* Bb = Bw + (size_t)bn*128*K;
  int wm = wave >> 1, wn = wave & 1;
  f32x4 acc[4][4] = {};

  stage32<512,256>(Ab, K, lsA[0], tid);
  stage32<512,256>(Bb, K, lsB[0], tid);
  int nk = K >> 5;
  for (int t = 0; t < nk; t++){
    __syncthreads();
    int cur = t & 1;
    if (t + 1 < nk){
      stage32<512,256>(Ab + ((t+1) << 5), K, lsA[cur^1], tid);
      stage32<512,256>(Bb + ((t+1) << 5), K, lsB[cur^1], tid);
    }
    const u16* la = lsA[cur];
    const u16* lb = lsB[cur];
    bf16x8 af[4], bfr[4];
#pragma unroll
    for (int mf = 0; mf < 4; mf++){
      int row = wm*64 + mf*16 + l16;
      af[mf] = *(const bf16x8*)(la + row*32 + ((grp ^ (row & 3)) << 3));
    }
#pragma unroll
    for (int nf = 0; nf < 4; nf++){
      int row = wn*64 + nf*16 + l16;
      bfr[nf] = *(const bf16x8*)(lb + row*32 + ((grp ^ (row & 3)) << 3));
    }
#pragma unroll
    for (int mf = 0; mf < 4; mf++)
#pragma unroll
      for (int nf = 0; nf < 4; nf++)
        acc[mf][nf] = mfma_bf16(af[mf], bfr[nf], acc[mf][nf]);
  }

  int mrow0 = bm*128 + wm*64;
  int f0 = bn*128 + wn*64;
#pragma unroll
  for (int nf = 0; nf < 4; nf++){
    int f = f0 + nf*16 + l16;
    float bv = bias[f];
#pragma unroll
    for (int mf = 0; mf < 4; mf++){
      int mbase = mrow0 + mf*16 + grp*4;
#pragma unroll
      for (int r = 0; r < 4; r++)
        Co[(size_t)(mbase + r)*Nf + f] = acc[mf][nf][r] + bv;
    }
  }
}

// ---------- QKV GEMM: 256x256 / BK=64, m201-anatomy 8-phase schedule ----------
// 8 waves (2Mx4N), per-wave 128x64 output, interleaved rows (m -> (m*2+wr)*16).
// 2 LDS dbuf (128KB, 1 block/CU). 8 phases per 2 K-tiles; per phase:
//   {ds_read quadrant frags; stage ONE half-tile (2 gloads); s_barrier;
//    lgkmcnt(0); setprio(1) 16 MFMA setprio(0); s_barrier}
// Quadrants per tile: Q1(A0,B0) Q2(A1,B0-kept) Q3(A1-kept,B1) Q4(A0-reread,B1).
// Stage schedule (iter j, tiles a=2j in buf0, a+1 in buf1):
//   ph1:A0(2j+1)->buf1  ph2:B1(2j+1)->buf1  ph3:B0(2j+2)->buf0
//   ph4:A1(2j+2)->buf0  ph5:A0(2j+2)->buf0  ph6:B1(2j+2)->buf0
//   ph7:B0(2j+3)->buf1  ph8:A1(2j+3)->buf1
// Every stage targets a slot whose last ds_read completed >=1 closing-barrier
// earlier. vmcnt(4) ONLY at end of ph4/ph8 (before the closing barrier):
// verifies exactly the halves consumed before the next vmcnt point; steady
// outstanding = 2 halves (4 loads). Barriers are asm s_barrier with "memory"
// clobber so ds_reads cannot hoist across. No sched_barrier (m141 lesson).
__launch_bounds__(512, 1)
__global__ void gemm_qkv(const u16* __restrict__ A, const u16* __restrict__ Bw,
                         const float* __restrict__ bias,
                         u16* __restrict__ Qp, u16* __restrict__ Kp,
                         u16* __restrict__ Vt, int M, int Nf, int K)
{
  __shared__ u16 lsA[2][256*64];
  __shared__ u16 lsB[2][256*64];
  int tid = threadIdx.x;
  int lane = tid & 63, grp = lane >> 4, l16 = lane & 15;
  int wave = tid >> 6;
  int wr = wave >> 2, wc = wave & 3;          // 2 x 4 wave grid
  int ntn = Nf >> 8;                          // 12
  int bid = (blockIdx.x & 7) * 48 + (blockIdx.x >> 3);
  int bm = bid / ntn, bn = bid % ntn;
  const u16* Ab = A + (size_t)bm*256*K;
  const u16* Bb = Bw + (size_t)bn*256*K;

  f32x4 acc[8][4] = {};

  // stage one 128-row half (h=0,1) of a 256x64 K-tile; 2 chunks/thread.
  auto stageHalf = [&](const u16* src, u16* lds, int h){
#pragma unroll
    for (int i = 0; i < 2; i++){
      int c = i*512 + tid;
      int row = h*128 + (c >> 3);
      int col = (((c & 7) ^ (row & 7)) << 3);
      gload16(src + (size_t)row*K + col, lds + h*8192 + ((size_t)(c & ~63) << 3));
    }
  };
  // read 4 A-frags (m = mo..mo+3, rows (m*2+wr)*16) from buffer la
  auto readA = [&](const u16* la, int mo, bf16x8 (&af)[4][2]){
#pragma unroll
    for (int m = 0; m < 4; m++){
      int grow = ((m+mo)*2 + wr)*16 + l16;
#pragma unroll
      for (int ks = 0; ks < 2; ks++)
        af[m][ks] = *(const bf16x8*)(la + grow*64 + (((ks*4+grp) ^ (grow & 7)) << 3));
    }
  };
  // read 2 B-frags (n = no..no+1, rows (n*4+wc)*16) from buffer lb
  auto readB = [&](const u16* lb, int no, bf16x8 (&bf)[2][2]){
#pragma unroll
    for (int n = 0; n < 2; n++){
      int brow = ((n+no)*4 + wc)*16 + l16;
#pragma unroll
      for (int ks = 0; ks < 2; ks++)
        bf[n][ks] = *(const bf16x8*)(lb + brow*64 + (((ks*4+grp) ^ (brow & 7)) << 3));
    }
  };
  auto mmaQ = [&](bf16x8 (&af)[4][2], bf16x8 (&bf)[2][2], int mo, int no){
    __builtin_amdgcn_s_setprio(1);
#pragma unroll
    for (int m = 0; m < 4; m++)
#pragma unroll
      for (int n = 0; n < 2; n++)
#pragma unroll
        for (int ks = 0; ks < 2; ks++)
          acc[m+mo][n+no] = mfma_bf16(af[m][ks], bf[n][ks], acc[m+mo][n+no]);
    __builtin_amdgcn_s_setprio(0);
  };
#define QBAR() asm volatile("s_barrier" ::: "memory")
#define QLGKM() asm volatile("s_waitcnt lgkmcnt(0)" ::: "memory")

  // prologue: stage A0(0),B0(0),A1(0),B1(0),B0(1),A1(1); verify first 4 halves
  stageHalf(Ab, lsA[0], 0);
  stageHalf(Bb, lsB[0], 0);
  stageHalf(Ab, lsA[0], 1);
  stageHalf(Bb, lsB[0], 1);
  stageHalf(Bb + (1 << 6), lsB[1], 0);
  stageHalf(Ab + (1 << 6), lsA[1], 1);
  asm volatile("s_waitcnt vmcnt(4)" ::: "memory");
  QBAR();

  int nit = K >> 7;                           // 8 iterations, 2 K-tiles each
  for (int j = 0; j < nit; j++){
    const u16* la0 = lsA[0];
    const u16* lb0 = lsB[0];
    const u16* la1 = lsA[1];
    const u16* lb1 = lsB[1];
    int t1 = 2*j + 1, t2 = 2*j + 2, t3 = 2*j + 3;
    bool pf = (j < nit - 1);
    bf16x8 af[4][2], bf[2][2];

    // ---- ph1: Q1(tile 2j): read A0,B0; stage A0(t1)->buf1 ----
    readA(la0, 0, af); readB(lb0, 0, bf);
    stageHalf(Ab + (t1 << 6), lsA[1], 0);
    QBAR(); QLGKM();
    mmaQ(af, bf, 0, 0);
    QBAR();

    // ---- ph2: Q2: read A1; stage B1(t1)->buf1 ----
    readA(la0, 4, af);
    stageHalf(Bb + (t1 << 6), lsB[1], 1);
    QBAR(); QLGKM();
    mmaQ(af, bf, 4, 0);
    QBAR();

    // ---- ph3: Q3: read B1; stage B0(t2)->buf0 ----
    readB(lb0, 2, bf);
    if (pf) stageHalf(Bb + (t2 << 6), lsB[0], 0);
    QBAR(); QLGKM();
    mmaQ(af, bf, 4, 2);
    QBAR();

    // ---- ph4: Q4: re-read A0; stage A1(t2)->buf0; vmcnt ----
    readA(la0, 0, af);
    if (pf) stageHalf(Ab + (t2 << 6), lsA[0], 1);
    QBAR(); QLGKM();
    mmaQ(af, bf, 0, 2);
    if (pf) asm volatile("s_waitcnt vmcnt(4)" ::: "memory");
    else    asm volatile("s_waitcnt vmcnt(0)" ::: "memory");
    QBAR();

    // ---- ph5: Q1(tile 2j+1): read A0',B0'; stage A0(t2)->buf0 ----
    readA(la1, 0, af); readB(lb1, 0, bf);
    if (pf) stageHalf(Ab + (t2 << 6), lsA[0], 0);
    QBAR(); QLGKM();
    mmaQ(af, bf, 0, 0);
    QBAR();

    // ---- ph6: Q2': read A1'; stage B1(t2)->buf0 ----
    readA(la1, 4, af);
    if (pf) stageHalf(Bb + (t2 << 6), lsB[0], 1);
    QBAR(); QLGKM();
    mmaQ(af, bf, 4, 0);
    QBAR();

    // ---- ph7: Q3': read B1'; stage B0(t3)->buf1 ----
    readB(lb1, 2, bf);
    if (pf) stageHalf(Bb + (t3 << 6), lsB[1], 0);
    QBAR(); QLGKM();
    mmaQ(af, bf, 4, 2);
    QBAR();

    // ---- ph8: Q4': re-read A0'; stage A1(t3)->buf1; vmcnt ----
    readA(la1, 0, af);
    if (pf) stageHalf(Ab + (t3 << 6), lsA[1], 1);
    QBAR(); QLGKM();
    mmaQ(af, bf, 0, 2);
    if (pf) asm volatile("s_waitcnt vmcnt(4)" ::: "memory");
    QBAR();
  }
#undef QBAR
#undef QLGKM

  // epilogue: bias + split into Q(scaled)/K/Vt (interleaved rows)
#pragma unroll
  for (int n = 0; n < 4; n++){
    int f = bn*256 + (n*4 + wc)*16 + l16;
    float bv = bias[f];
    int h = f / 192, c = f % 192;             // f = h*3D + c, D=64
#pragma unroll
    for (int m = 0; m < 8; m++){
      int mbase = bm*256 + (m*2 + wr)*16 + grp*4;
      int bb = mbase >> 11, n0 = mbase & 2047;
      size_t bh = (size_t)bb*16 + h;
      if (c >= 128){
        ushort4 w;
        w.x = f2bf(acc[m][n][0] + bv);
        w.y = f2bf(acc[m][n][1] + bv);
        w.z = f2bf(acc[m][n][2] + bv);
        w.w = f2bf(acc[m][n][3] + bv);
        *(ushort4*)(Vt + (bh*64 + (size_t)(c - 128))*2048 + n0) = w;
      } else {
        u16* dst = (c < 64) ? Qp : Kp;
        float sc = (c < 64) ? 0.18033688011f : 1.0f;   // scale*log2e into Q
        int cc = c & 63;
#pragma unroll
        for (int r = 0; r < 4; r++)
          dst[(bh*2048 + n0 + r)*64 + cc] = f2bf((acc[m][n][r] + bv) * sc);
      }
    }
  }
}

// P-fragment pack: cvt_pk pairs + cross-half permlane32_swap (rounds 7-17).
__device__ __forceinline__ bf16x8 packP(const f32x16& pp, int base){
  unsigned t0 = cvtpk(pp[base+0], pp[base+1]);
  unsigned t1 = cvtpk(pp[base+2], pp[base+3]);
  unsigned t2 = cvtpk(pp[base+4], pp[base+5]);
  unsigned t3 = cvtpk(pp[base+6], pp[base+7]);
  i32x2 r02 = __builtin_amdgcn_permlane32_swap((int)t0, (int)t2, false, false);
  i32x2 r13 = __builtin_amdgcn_permlane32_swap((int)t1, (int)t3, false, false);
  union { unsigned u[4]; bf16x8 v; } pu;
  pu.u[0] = (unsigned)r02.x;
  pu.u[1] = (unsigned)r13.x;
  pu.u[2] = (unsigned)r02.y;
  pu.u[3] = (unsigned)r13.y;
  return pu.v;
}

__device__ __forceinline__ void expv16(f32x16& p){
#pragma unroll
  for (int r = 0; r < 16; r += 4){
    float a = p[r], b = p[r+1], c = p[r+2], d = p[r+3];
    exp4q(a, b, c, d);
    p[r] = a; p[r+1] = b; p[r+2] = c; p[r+3] = d;
  }
}

// Flash attention fwd (round-15/17 proven config: 8 waves x 32 q-rows,
// grid 512, 4-buffer counted-vmcnt LDS pipeline, one barrier per tile).
__launch_bounds__(512, 4)
__global__ void attn_fwd(const u16* __restrict__ Qg, const u16* __restrict__ Kg,
                         const u16* __restrict__ Vtg, u16* __restrict__ Oa)
{
  __shared__ u16 kl[4][64*64];
  __shared__ u16 vl[4][64*64];
  int tid = threadIdx.x;
  int lane = tid & 63, wave = tid >> 6;
  int q32 = lane & 31, hi = lane >> 5;
  int bid = (blockIdx.x & 7) * 64 + (blockIdx.x >> 3);
  int bh = bid >> 3, qt = bid & 7;
  int b = bh >> 4, h = bh & 15;
  int q0 = qt*256 + wave*32;
  const u16* Qb = Qg + ((size_t)bh*2048 + q0)*64;
  const u16* Kb = Kg + (size_t)bh*2048*64;
  const u16* Vb = Vtg + (size_t)bh*64*2048;

  bf16x8 qf[4];
#pragma unroll
  for (int s = 0; s < 4; s++)
    qf[s] = *(const bf16x8*)(Qb + q32*64 + s*16 + hi*8);

  f32x16 lacc = {};
  f32x16 oacc[2] = {};

#pragma unroll
  for (int t = 0; t < 3; t++){
    stage64<512>(Kb + (size_t)t*64*64, 64, kl[t], tid);
    stage64<512>(Vb + t*64, 2048, vl[t], tid);
  }

  for (int kt = 0; kt < 32; kt++){
    if (kt < 30)       asm volatile("s_waitcnt vmcnt(4)" ::: "memory");
    else if (kt == 30) asm volatile("s_waitcnt vmcnt(2)" ::: "memory");
    else               asm volatile("s_waitcnt vmcnt(0)" ::: "memory");
    __builtin_amdgcn_s_barrier();
    __builtin_amdgcn_sched_barrier(0);
    if (kt + 3 < 32){
      stage64<512>(Kb + (size_t)(kt+3)*64*64, 64, kl[(kt+3)&3], tid);
      stage64<512>(Vb + (kt+3)*64, 2048, vl[(kt+3)&3], tid);
    }
    const u16* lk = kl[kt & 3];
    const u16* lv = vl[kt & 3];

    f32x16 p0 = {}, p1 = {};
    __builtin_amdgcn_s_setprio(1);
#pragma unroll
    for (int s = 0; s < 4; s++){
      int r0 = q32;
      bf16x8 k0 = *(const bf16x8*)(lk + r0*64 + (((s*2+hi) ^ (r0 & 7)) << 3));
      p0 = mfma32(k0, qf[s], p0);
      int r1 = 32 + q32;
      bf16x8 k1 = *(const bf16x8*)(lk + r1*64 + (((s*2+hi) ^ (r1 & 7)) << 3));
      p1 = mfma32(k1, qf[s], p1);
    }
    __builtin_amdgcn_s_setprio(0);

    expv16(p0); expv16(p1);
#pragma unroll
    for (int r = 0; r < 16; r++) lacc[r] += p0[r];
#pragma unroll
    for (int r = 0; r < 16; r++) lacc[r] += p1[r];

#pragma unroll
    for (int ks = 0; ks < 4; ks++){
      bf16x8 pb = packP((ks < 2) ? p0 : p1, (ks & 1) * 8);
      __builtin_amdgcn_s_setprio(1);
      int rowd0 = q32;
      bf16x8 v0 = *(const bf16x8*)(lv + rowd0*64 + (((ks*2+hi) ^ (rowd0 & 7)) << 3));
      oacc[0] = mfma32(v0, pb, oacc[0]);
      int rowd1 = 32 + q32;
      bf16x8 v1 = *(const bf16x8*)(lv + rowd1*64 + (((ks*2+hi) ^ (rowd1 & 7)) << 3));
      oacc[1] = mfma32(v1, pb, oacc[1]);
      __builtin_amdgcn_s_setprio(0);
    }
  }

#pragma unroll
  for (int r = 0; r < 8; r++) lacc[r] += lacc[r+8];
#pragma unroll
  for (int r = 0; r < 4; r++) lacc[r] += lacc[r+4];
  float l = (lacc[0] + lacc[1]) + (lacc[2] + lacc[3]);
  l += __shfl_xor(l, 32, 64);
  float inv = 1.0f / l;

  size_t obase = ((size_t)b*2048 + q0 + q32)*1024 + h*64;
#pragma unroll
  for (int dblk = 0; dblk < 2; dblk++)
#pragma unroll
    for (int rb = 0; rb < 4; rb++){
      ushort4 w;
      w.x = f2bf(oacc[dblk][rb*4+0] * inv);
      w.y = f2bf(oacc[dblk][rb*4+1] * inv);
      w.z = f2bf(oacc[dblk][rb*4+2] * inv);
      w.w = f2bf(oacc[dblk][rb*4+3] * inv);
      *(ushort4*)(Oa + obase + dblk*32 + rb*8 + hi*4) = w;
    }
}

extern "C" void kernel_launch(void* const* d_in, const int* in_sizes, int n_in,
                              void* d_out, int out_size, void* d_ws, size_t ws_size,
                              hipStream_t stream)
{
  const float* x    = (const float*)d_in[0];
  const float* qkvw = (const float*)d_in[1];
  const float* qkvb = (const float*)d_in[2];
  const float* ow   = (const float*)d_in[3];
  const float* ob   = (const float*)d_in[4];
  float* out = (float*)d_out;

  u16* xb = (u16*)d_ws;                       // 8192*1024 bf16
  u16* wq = xb + (size_t)8192*1024;           // 3072*1024
  u16* wo = wq + (size_t)3072*1024;           // 1024*1024
  u16* Qp = wo + (size_t)1024*1024;           // 64*2048*64 (pre-scaled)
  u16* Kp = Qp + (size_t)64*2048*64;
  u16* Vt = Kp + (size_t)64*2048*64;          // transposed [bh][d][n]
  u16* Oa = Vt + (size_t)64*2048*64;          // 8192*1024

  // fused converts: x (2.09M float4) + qkv_w (0.79M) + o_w (0.26M)
  cvt_all<<<2048, 256, 0, stream>>>(x, qkvw, ow, xb, wq, wo,
                                    (8192*1024)/4, (3072*1024)/4, (1024*1024)/4);

  gemm_qkv<<<32*12, 512, 0, stream>>>(xb, wq, qkvb, Qp, Kp, Vt, 8192, 3072, 1024);
  attn_fwd<<<512, 512, 0, stream>>>(Qp, Kp, Vt, Oa);
  gemm_bt1<<<64*8, 256, 0, stream>>>(Oa, wo, ob, out, 8192, 1024, 1024);
}

// Round 19
// 190.140 us; speedup vs baseline: 1.0365x; 1.0365x over previous
//
#include <hip/hip_runtime.h>

typedef unsigned short u16;
typedef float f32x4 __attribute__((ext_vector_type(4)));
typedef float f32x16 __attribute__((ext_vector_type(16)));
typedef short bf16x8 __attribute__((ext_vector_type(8)));
typedef int i32x2 __attribute__((ext_vector_type(2)));

__device__ __forceinline__ u16 f2bf(float f){
  union { float f; unsigned u; } x; x.f = f;
  unsigned r = (x.u + 0x7FFFu + ((x.u >> 16) & 1u)) >> 16;
  return (u16)r;
}

// packed bf16 convert: dst.lo = bf16(lo), dst.hi = bf16(hi)  [verified round 4]
__device__ __forceinline__ unsigned cvtpk(float lo, float hi){
  unsigned r;
  asm("v_cvt_pk_bf16_f32 %0, %1, %2" : "=v"(r) : "v"(lo), "v"(hi));
  return r;
}

// 4x guarded raw v_exp_f32 (D = 2^S0). TRANS->TRANS back-to-back needs no
// wait state; one s_nop 1 closes the TRANS->VALU hazard for the tail def.
__device__ __forceinline__ void exp4q(float& a, float& b, float& c, float& d){
  asm("v_exp_f32 %0, %0\n\t"
      "v_exp_f32 %1, %1\n\t"
      "v_exp_f32 %2, %2\n\t"
      "v_exp_f32 %3, %3\n\t"
      "s_nop 1"
      : "+v"(a), "+v"(b), "+v"(c), "+v"(d));
}

__device__ __forceinline__ f32x4 mfma_bf16(bf16x8 a, bf16x8 b, f32x4 c){
  return __builtin_amdgcn_mfma_f32_16x16x32_bf16(a, b, c, 0, 0, 0);
}

__device__ __forceinline__ f32x16 mfma32(bf16x8 a, bf16x8 b, f32x16 c){
  return __builtin_amdgcn_mfma_f32_32x32x16_bf16(a, b, c, 0, 0, 0);
}

__device__ __forceinline__ void gload16(const u16* g, u16* l){
  __builtin_amdgcn_global_load_lds((__attribute__((address_space(1))) void*)g,
                                   (__attribute__((address_space(3))) void*)l, 16, 0, 0);
}

// ---------------- fused fp32 -> bf16 converts (x, qkv_w, o_w in one launch) ----
__global__ void cvt_all(const float* __restrict__ x, const float* __restrict__ w1,
                        const float* __restrict__ w2,
                        u16* __restrict__ ox, u16* __restrict__ o1, u16* __restrict__ o2,
                        int nx4, int n14, int n24){
  int stride = gridDim.x * blockDim.x;
  int ntot = nx4 + n14 + n24;
  for (int i = blockIdx.x*blockDim.x + threadIdx.x; i < ntot; i += stride){
    const float* src; u16* dst; int j = i;
    if (j < nx4){ src = x; dst = ox; }
    else if (j < nx4 + n14){ j -= nx4; src = w1; dst = o1; }
    else { j -= nx4 + n14; src = w2; dst = o2; }
    float4 v = ((const float4*)src)[j];
    ushort4 o;
    o.x = f2bf(v.x); o.y = f2bf(v.y); o.z = f2bf(v.z); o.w = f2bf(v.w);
    ((ushort4*)dst)[j] = o;
  }
}

// Generic 16B-chunk stager for [rows][32] bf16 tiles (4 slots/row, slot ^= row&3).
template<int NCH, int NTHR>
__device__ __forceinline__ void stage32(const u16* src, int ld, u16* lds, int tid){
#pragma unroll
  for (int i = 0; i < NCH/NTHR; i++){
    int c = i*NTHR + tid;
    int row = c >> 2, slot = c & 3;
    int col = ((slot ^ (row & 3)) << 3);
    gload16(src + (size_t)row*ld + col, lds + ((size_t)(c & ~63) << 3));
  }
}

// 64x64 bf16 tile stager (8 slots/row, slot ^= row&7).
template<int NTHR>
__device__ __forceinline__ void stage64(const u16* src, int ld, u16* lds, int tid){
#pragma unroll
  for (int i = 0; i < 512/NTHR; i++){
    int c = i*NTHR + tid;
    int row = c >> 3, slot = c & 7;
    int col = ((slot ^ (row & 7)) << 3);
    gload16(src + (size_t)row*ld + col, lds + ((size_t)(c & ~63) << 3));
  }
}

// ---------- o-proj GEMM (proven 128x128 2-phase path) ----------
__launch_bounds__(256)
__global__ void gemm_bt1(const u16* __restrict__ A, const u16* __restrict__ Bw,
                         const float* __restrict__ bias, float* __restrict__ Co,
                         int M, int Nf, int K)
{
  __shared__ u16 lsA[2][128*32];
  __shared__ u16 lsB[2][128*32];
  int tid = threadIdx.x;
  int wave = tid >> 6, lane = tid & 63, grp = lane >> 4, l16 = lane & 15;
  int ntn = Nf >> 7;
  int bm = blockIdx.x / ntn, bn = blockIdx.x % ntn;
  const u16* Ab = A + (size_t)bm*128*K;
  const u16* Bb = Bw + (size_t)bn*128*K;
  int wm = wave >> 1, wn = wave & 1;
  f32x4 acc[4][4] = {};

  stage32<512,256>(Ab, K, lsA[0], tid);
  stage32<512,256>(Bb, K, lsB[0], tid);
  int nk = K >> 5;
  for (int t = 0; t < nk; t++){
    __syncthreads();
    int cur = t & 1;
    if (t + 1 < nk){
      stage32<512,256>(Ab + ((t+1) << 5), K, lsA[cur^1], tid);
      stage32<512,256>(Bb + ((t+1) << 5), K, lsB[cur^1], tid);
    }
    const u16* la = lsA[cur];
    const u16* lb = lsB[cur];
    bf16x8 af[4], bfr[4];
#pragma unroll
    for (int mf = 0; mf < 4; mf++){
      int row = wm*64 + mf*16 + l16;
      af[mf] = *(const bf16x8*)(la + row*32 + ((grp ^ (row & 3)) << 3));
    }
#pragma unroll
    for (int nf = 0; nf < 4; nf++){
      int row = wn*64 + nf*16 + l16;
      bfr[nf] = *(const bf16x8*)(lb + row*32 + ((grp ^ (row & 3)) << 3));
    }
#pragma unroll
    for (int mf = 0; mf < 4; mf++)
#pragma unroll
      for (int nf = 0; nf < 4; nf++)
        acc[mf][nf] = mfma_bf16(af[mf], bfr[nf], acc[mf][nf]);
  }

  int mrow0 = bm*128 + wm*64;
  int f0 = bn*128 + wn*64;
#pragma unroll
  for (int nf = 0; nf < 4; nf++){
    int f = f0 + nf*16 + l16;
    float bv = bias[f];
#pragma unroll
    for (int mf = 0; mf < 4; mf++){
      int mbase = mrow0 + mf*16 + grp*4;
#pragma unroll
      for (int r = 0; r < 4; r++)
        Co[(size_t)(mbase + r)*Nf + f] = acc[mf][nf][r] + bv;
    }
  }
}

// ---------- QKV GEMM: 256x256 / BK=64 counted-vmcnt pipeline (round 15/17) ----------
// Best measured QKV structure (~92 us, 572 TF). 8-phase variants regressed
// (r13: 126, r18: 102): at K=1024 only 16 K-steps exist — extra barrier
// crossings cost more than the deeper pipeline saves. 2-phase-class ceiling.
__launch_bounds__(512, 1)
__global__ void gemm_qkv(const u16* __restrict__ A, const u16* __restrict__ Bw,
                         const float* __restrict__ bias,
                         u16* __restrict__ Qp, u16* __restrict__ Kp,
                         u16* __restrict__ Vt, int M, int Nf, int K)
{
  __shared__ u16 lsA[2][256*64];
  __shared__ u16 lsB[2][256*64];
  int tid = threadIdx.x;
  int lane = tid & 63, grp = lane >> 4, l16 = lane & 15;
  int wave = tid >> 6;
  int wr = wave >> 2, wc = wave & 3;          // 2 x 4 wave grid
  int ntn = Nf >> 8;                          // 12
  int bid = (blockIdx.x & 7) * 48 + (blockIdx.x >> 3);
  int bm = bid / ntn, bn = bid % ntn;
  const u16* Ab = A + (size_t)bm*256*K;
  const u16* Bb = Bw + (size_t)bn*256*K;

  f32x4 acc[8][4] = {};

  auto stageHalf = [&](const u16* src, u16* lds, int h){
#pragma unroll
    for (int i = 0; i < 2; i++){
      int c = i*512 + tid;
      int row = h*128 + (c >> 3);
      int col = (((c & 7) ^ (row & 7)) << 3);
      gload16(src + (size_t)row*K + col, lds + h*8192 + ((size_t)(c & ~63) << 3));
    }
  };

  stageHalf(Ab, lsA[0], 0);
  stageHalf(Bb, lsB[0], 0);
  stageHalf(Ab, lsA[0], 1);
  stageHalf(Bb, lsB[0], 1);
  asm volatile("s_waitcnt vmcnt(4)" ::: "memory");

  int nkt = K >> 6;                           // 16
  for (int t = 0; t < nkt; t++){
    const u16* la = lsA[t & 1];
    const u16* lb = lsB[t & 1];
    const u16* As = Ab + ((t+1) << 6);
    const u16* Bs = Bb + ((t+1) << 6);
    u16* dA = lsA[(t+1) & 1];
    u16* dB = lsB[(t+1) & 1];
    bool pf = (t + 1) < nkt;
    bf16x8 af[4][2], bf[2][2];

    // ---- p0 ----
    __builtin_amdgcn_s_barrier();
#pragma unroll
    for (int m = 0; m < 4; m++){
      int grow = (m*2 + wr)*16 + l16;
#pragma unroll
      for (int ks = 0; ks < 2; ks++)
        af[m][ks] = *(const bf16x8*)(la + grow*64 + (((ks*4+grp) ^ (grow & 7)) << 3));
    }
#pragma unroll
    for (int n = 0; n < 2; n++){
      int brow = (n*4 + wc)*16 + l16;
#pragma unroll
      for (int ks = 0; ks < 2; ks++)
        bf[n][ks] = *(const bf16x8*)(lb + brow*64 + (((ks*4+grp) ^ (brow & 7)) << 3));
    }
    if (pf) stageHalf(As, dA, 0);
    __builtin_amdgcn_s_setprio(1);
#pragma unroll
    for (int m = 0; m < 4; m++)
#pragma unroll
      for (int n = 0; n < 2; n++)
#pragma unroll
        for (int ks = 0; ks < 2; ks++)
          acc[m][n] = mfma_bf16(af[m][ks], bf[n][ks], acc[m][n]);
    __builtin_amdgcn_s_setprio(0);
    if (pf) asm volatile("s_waitcnt vmcnt(4)" ::: "memory");
    else    asm volatile("s_waitcnt vmcnt(2)" ::: "memory");

    // ---- p1 ----
    __builtin_amdgcn_s_barrier();
#pragma unroll
    for (int m = 0; m < 4; m++){
      int grow = ((m+4)*2 + wr)*16 + l16;
#pragma unroll
      for (int ks = 0; ks < 2; ks++)
        af[m][ks] = *(const bf16x8*)(la + grow*64 + (((ks*4+grp) ^ (grow & 7)) << 3));
    }
    if (pf) stageHalf(Bs, dB, 0);
    __builtin_amdgcn_s_setprio(1);
#pragma unroll
    for (int m = 0; m < 4; m++)
#pragma unroll
      for (int n = 0; n < 2; n++)
#pragma unroll
        for (int ks = 0; ks < 2; ks++)
          acc[m+4][n] = mfma_bf16(af[m][ks], bf[n][ks], acc[m+4][n]);
    __builtin_amdgcn_s_setprio(0);
    if (pf) asm volatile("s_waitcnt vmcnt(4)" ::: "memory");
    else    asm volatile("s_waitcnt vmcnt(0)" ::: "memory");

    // ---- p2 ----
    __builtin_amdgcn_s_barrier();
#pragma unroll
    for (int n = 0; n < 2; n++){
      int brow = ((n+2)*4 + wc)*16 + l16;
#pragma unroll
      for (int ks = 0; ks < 2; ks++)
        bf[n][ks] = *(const bf16x8*)(lb + brow*64 + (((ks*4+grp) ^ (brow & 7)) << 3));
    }
    if (pf) stageHalf(As, dA, 1);
    __builtin_amdgcn_s_setprio(1);
#pragma unroll
    for (int m = 0; m < 4; m++)
#pragma unroll
      for (int n = 0; n < 2; n++)
#pragma unroll
        for (int ks = 0; ks < 2; ks++)
          acc[m+4][n+2] = mfma_bf16(af[m][ks], bf[n][ks], acc[m+4][n+2]);
    __builtin_amdgcn_s_setprio(0);

    // ---- p3 ----
#pragma unroll
    for (int m = 0; m < 4; m++){
      int grow = (m*2 + wr)*16 + l16;
#pragma unroll
      for (int ks = 0; ks < 2; ks++)
        af[m][ks] = *(const bf16x8*)(la + grow*64 + (((ks*4+grp) ^ (grow & 7)) << 3));
    }
    if (pf) stageHalf(Bs, dB, 1);
    __builtin_amdgcn_s_setprio(1);
#pragma unroll
    for (int m = 0; m < 4; m++)
#pragma unroll
      for (int n = 0; n < 2; n++)
#pragma unroll
        for (int ks = 0; ks < 2; ks++)
          acc[m][n+2] = mfma_bf16(af[m][ks], bf[n][ks], acc[m][n+2]);
    __builtin_amdgcn_s_setprio(0);
    if (pf) asm volatile("s_waitcnt vmcnt(4)" ::: "memory");
  }

  // epilogue: bias + split into Q(scaled)/K/Vt (interleaved rows)
#pragma unroll
  for (int n = 0; n < 4; n++){
    int f = bn*256 + (n*4 + wc)*16 + l16;
    float bv = bias[f];
    int h = f / 192, c = f % 192;             // f = h*3D + c, D=64
#pragma unroll
    for (int m = 0; m < 8; m++){
      int mbase = bm*256 + (m*2 + wr)*16 + grp*4;
      int bb = mbase >> 11, n0 = mbase & 2047;
      size_t bh = (size_t)bb*16 + h;
      if (c >= 128){
        ushort4 w;
        w.x = f2bf(acc[m][n][0] + bv);
        w.y = f2bf(acc[m][n][1] + bv);
        w.z = f2bf(acc[m][n][2] + bv);
        w.w = f2bf(acc[m][n][3] + bv);
        *(ushort4*)(Vt + (bh*64 + (size_t)(c - 128))*2048 + n0) = w;
      } else {
        u16* dst = (c < 64) ? Qp : Kp;
        float sc = (c < 64) ? 0.18033688011f : 1.0f;
        int cc = c & 63;
#pragma unroll
        for (int r = 0; r < 4; r++)
          dst[(bh*2048 + n0 + r)*64 + cc] = f2bf((acc[m][n][r] + bv) * sc);
      }
    }
  }
}

// P-fragment pack: cvt_pk pairs + cross-half permlane32_swap (rounds 7-17).
__device__ __forceinline__ bf16x8 packP(const f32x16& pp, int base){
  unsigned t0 = cvtpk(pp[base+0], pp[base+1]);
  unsigned t1 = cvtpk(pp[base+2], pp[base+3]);
  unsigned t2 = cvtpk(pp[base+4], pp[base+5]);
  unsigned t3 = cvtpk(pp[base+6], pp[base+7]);
  i32x2 r02 = __builtin_amdgcn_permlane32_swap((int)t0, (int)t2, false, false);
  i32x2 r13 = __builtin_amdgcn_permlane32_swap((int)t1, (int)t3, false, false);
  union { unsigned u[4]; bf16x8 v; } pu;
  pu.u[0] = (unsigned)r02.x;
  pu.u[1] = (unsigned)r13.x;
  pu.u[2] = (unsigned)r02.y;
  pu.u[3] = (unsigned)r13.y;
  return pu.v;
}

__device__ __forceinline__ void expv16(f32x16& p){
#pragma unroll
  for (int r = 0; r < 16; r += 4){
    float a = p[r], b = p[r+1], c = p[r+2], d = p[r+3];
    exp4q(a, b, c, d);
    p[r] = a; p[r+1] = b; p[r+2] = c; p[r+3] = d;
  }
}

// Flash attention fwd (round-15/17 proven config: 8 waves x 32 q-rows,
// grid 512, 4-buffer counted-vmcnt LDS pipeline, one barrier per tile).
__launch_bounds__(512, 4)
__global__ void attn_fwd(const u16* __restrict__ Qg, const u16* __restrict__ Kg,
                         const u16* __restrict__ Vtg, u16* __restrict__ Oa)
{
  __shared__ u16 kl[4][64*64];
  __shared__ u16 vl[4][64*64];
  int tid = threadIdx.x;
  int lane = tid & 63, wave = tid >> 6;
  int q32 = lane & 31, hi = lane >> 5;
  int bid = (blockIdx.x & 7) * 64 + (blockIdx.x >> 3);
  int bh = bid >> 3, qt = bid & 7;
  int b = bh >> 4, h = bh & 15;
  int q0 = qt*256 + wave*32;
  const u16* Qb = Qg + ((size_t)bh*2048 + q0)*64;
  const u16* Kb = Kg + (size_t)bh*2048*64;
  const u16* Vb = Vtg + (size_t)bh*64*2048;

  bf16x8 qf[4];
#pragma unroll
  for (int s = 0; s < 4; s++)
    qf[s] = *(const bf16x8*)(Qb + q32*64 + s*16 + hi*8);

  f32x16 lacc = {};
  f32x16 oacc[2] = {};

#pragma unroll
  for (int t = 0; t < 3; t++){
    stage64<512>(Kb + (size_t)t*64*64, 64, kl[t], tid);
    stage64<512>(Vb + t*64, 2048, vl[t], tid);
  }

  for (int kt = 0; kt < 32; kt++){
    if (kt < 30)       asm volatile("s_waitcnt vmcnt(4)" ::: "memory");
    else if (kt == 30) asm volatile("s_waitcnt vmcnt(2)" ::: "memory");
    else               asm volatile("s_waitcnt vmcnt(0)" ::: "memory");
    __builtin_amdgcn_s_barrier();
    __builtin_amdgcn_sched_barrier(0);
    if (kt + 3 < 32){
      stage64<512>(Kb + (size_t)(kt+3)*64*64, 64, kl[(kt+3)&3], tid);
      stage64<512>(Vb + (kt+3)*64, 2048, vl[(kt+3)&3], tid);
    }
    const u16* lk = kl[kt & 3];
    const u16* lv = vl[kt & 3];

    f32x16 p0 = {}, p1 = {};
    __builtin_amdgcn_s_setprio(1);
#pragma unroll
    for (int s = 0; s < 4; s++){
      int r0 = q32;
      bf16x8 k0 = *(const bf16x8*)(lk + r0*64 + (((s*2+hi) ^ (r0 & 7)) << 3));
      p0 = mfma32(k0, qf[s], p0);
      int r1 = 32 + q32;
      bf16x8 k1 = *(const bf16x8*)(lk + r1*64 + (((s*2+hi) ^ (r1 & 7)) << 3));
      p1 = mfma32(k1, qf[s], p1);
    }
    __builtin_amdgcn_s_setprio(0);

    expv16(p0); expv16(p1);
#pragma unroll
    for (int r = 0; r < 16; r++) lacc[r] += p0[r];
#pragma unroll
    for (int r = 0; r < 16; r++) lacc[r] += p1[r];

#pragma unroll
    for (int ks = 0; ks < 4; ks++){
      bf16x8 pb = packP((ks < 2) ? p0 : p1, (ks & 1) * 8);
      __builtin_amdgcn_s_setprio(1);
      int rowd0 = q32;
      bf16x8 v0 = *(const bf16x8*)(lv + rowd0*64 + (((ks*2+hi) ^ (rowd0 & 7)) << 3));
      oacc[0] = mfma32(v0, pb, oacc[0]);
      int rowd1 = 32 + q32;
      bf16x8 v1 = *(const bf16x8*)(lv + rowd1*64 + (((ks*2+hi) ^ (rowd1 & 7)) << 3));
      oacc[1] = mfma32(v1, pb, oacc[1]);
      __builtin_amdgcn_s_setprio(0);
    }
  }

#pragma unroll
  for (int r = 0; r < 8; r++) lacc[r] += lacc[r+8];
#pragma unroll
  for (int r = 0; r < 4; r++) lacc[r] += lacc[r+4];
  float l = (lacc[0] + lacc[1]) + (lacc[2] + lacc[3]);
  l += __shfl_xor(l, 32, 64);
  float inv = 1.0f / l;

  size_t obase = ((size_t)b*2048 + q0 + q32)*1024 + h*64;
#pragma unroll
  for (int dblk = 0; dblk < 2; dblk++)
#pragma unroll
    for (int rb = 0; rb < 4; rb++){
      ushort4 w;
      w.x = f2bf(oacc[dblk][rb*4+0] * inv);
      w.y = f2bf(oacc[dblk][rb*4+1] * inv);
      w.z = f2bf(oacc[dblk][rb*4+2] * inv);
      w.w = f2bf(oacc[dblk][rb*4+3] * inv);
      *(ushort4*)(Oa + obase + dblk*32 + rb*8 + hi*4) = w;
    }
}

extern "C" void kernel_launch(void* const* d_in, const int* in_sizes, int n_in,
                              void* d_out, int out_size, void* d_ws, size_t ws_size,
                              hipStream_t stream)
{
  const float* x    = (const float*)d_in[0];
  const float* qkvw = (const float*)d_in[1];
  const float* qkvb = (const float*)d_in[2];
  const float* ow   = (const float*)d_in[3];
  const float* ob   = (const float*)d_in[4];
  float* out = (float*)d_out;

  u16* xb = (u16*)d_ws;                       // 8192*1024 bf16
  u16* wq = xb + (size_t)8192*1024;           // 3072*1024
  u16* wo = wq + (size_t)3072*1024;           // 1024*1024
  u16* Qp = wo + (size_t)1024*1024;           // 64*2048*64 (pre-scaled)
  u16* Kp = Qp + (size_t)64*2048*64;
  u16* Vt = Kp + (size_t)64*2048*64;          // transposed [bh][d][n]
  u16* Oa = Vt + (size_t)64*2048*64;          // 8192*1024

  // fused converts: x (2.09M float4) + qkv_w (0.79M) + o_w (0.26M)
  cvt_all<<<2048, 256, 0, stream>>>(x, qkvw, ow, xb, wq, wo,
                                    (8192*1024)/4, (3072*1024)/4, (1024*1024)/4);

  gemm_qkv<<<32*12, 512, 0, stream>>>(xb, wq, qkvb, Qp, Kp, Vt, 8192, 3072, 1024);
  attn_fwd<<<512, 512, 0, stream>>>(Qp, Kp, Vt, Oa);
  gemm_bt1<<<64*8, 256, 0, stream>>>(Oa, wo, ob, out, 8192, 1024, 1024);
}